// Round 1
// baseline (2178.524 us; speedup 1.0000x reference)
//
#include <hip/hip_runtime.h>
#include <math.h>

#define CCH  384
#define BATCH 8
#define HWN  4096
#define IMG  64
#define NG   32
#define CPG  12
#define KSEL 512
#define FFTP 65   // LDS pitch: 64+1 kills column-pass bank conflicts

__device__ __forceinline__ unsigned br6(unsigned i) {
  return ((i&1u)<<5)|((i&2u)<<3)|((i&4u)<<1)|((i&8u)>>1)|((i&16u)>>3)|((i&32u)>>5);
}
// monotone float->uint key: larger float -> larger key
__device__ __forceinline__ unsigned f2key(float f) {
  unsigned u = __float_as_uint(f);
  return (u & 0x80000000u) ? ~u : (u | 0x80000000u);
}
__device__ __forceinline__ float wave_max(float v) {
#pragma unroll
  for (int o = 32; o > 0; o >>= 1) v = fmaxf(v, __shfl_down(v, o, 64));
  return v;
}
__device__ __forceinline__ float wave_sum(float v) {
#pragma unroll
  for (int o = 32; o > 0; o >>= 1) v += __shfl_down(v, o, 64);
  return v;
}

// ---------------- GroupNorm ----------------
__global__ __launch_bounds__(256) void gn_kernel(const float* __restrict__ x,
    const float* __restrict__ gamma, const float* __restrict__ beta,
    float* __restrict__ xn) {
  int b = blockIdx.x >> 5, g = blockIdx.x & 31;
  size_t base = ((size_t)b * CCH + (size_t)g * CPG) * HWN;
  const float4* xp = (const float4*)(x + base);
  float4* op = (float4*)(xn + base);
  int tid = threadIdx.x;
  const int N4 = CPG * HWN / 4;  // 12288
  float s = 0.f, ss = 0.f;
  for (int i = tid; i < N4; i += 256) {
    float4 v = xp[i];
    s  += (v.x + v.y) + (v.z + v.w);
    ss += (v.x*v.x + v.y*v.y) + (v.z*v.z + v.w*v.w);
  }
  s = wave_sum(s); ss = wave_sum(ss);
  __shared__ float sb[4], qb[4], mb[2];
  int w = tid >> 6;
  if ((tid & 63) == 0) { sb[w] = s; qb[w] = ss; }
  __syncthreads();
  if (tid == 0) {
    float S = sb[0]+sb[1]+sb[2]+sb[3], Q = qb[0]+qb[1]+qb[2]+qb[3];
    float inv = 1.0f / (float)(CPG * HWN);
    float mu = S * inv;
    float var = Q * inv - mu * mu;
    mb[0] = mu; mb[1] = rsqrtf(var + 1e-5f);
  }
  __syncthreads();
  float mu = mb[0], rs = mb[1];
  for (int i = tid; i < N4; i += 256) {
    int ch = g * CPG + (i >> 10);
    float ga = gamma[ch] * rs;
    float be = beta[ch] - mu * ga;
    float4 v = xp[i];
    float4 o;
    o.x = v.x*ga + be; o.y = v.y*ga + be; o.z = v.z*ga + be; o.w = v.w*ga + be;
    op[i] = o;
  }
}

// ---------------- 1x1 conv as GEMM: Y[b,m,p] = sum_k W[m,k] X[b,k,p] + bias ---
// EPI==1: multiply result by xnm at the same address (final res*xn fusion)
template<int EPI>
__global__ __launch_bounds__(256) void gemm1x1_kernel(
    const float* __restrict__ Wt, const float* __restrict__ bias,
    const float* __restrict__ X, const float* __restrict__ xnm,
    float* __restrict__ Y) {
  const int K = CCH;
  int b  = blockIdx.z;
  int m0 = blockIdx.y * 64;
  int n0 = blockIdx.x * 64;
  const float* Xb = X + (size_t)b * CCH * HWN;
  __shared__ float As[16][64];
  __shared__ float Bs[16][64];
  int tid = threadIdx.x;
  int tx = tid & 15, ty = tid >> 4;
  float acc[4][4] = {{0.f}};
  int am = tid >> 2, ak = (tid & 3) << 2;
  int bk = tid >> 4, bn = (tid & 15) << 2;
  const float* ap = Wt + (size_t)(m0 + am) * K + ak;
  const float* bp = Xb + (size_t)bk * HWN + n0 + bn;
  for (int k0 = 0; k0 < K; k0 += 16) {
    float4 a4 = *(const float4*)ap; ap += 16;
    float4 b4 = *(const float4*)bp; bp += (size_t)16 * HWN;
    As[ak+0][am] = a4.x; As[ak+1][am] = a4.y; As[ak+2][am] = a4.z; As[ak+3][am] = a4.w;
    *(float4*)&Bs[bk][bn] = b4;
    __syncthreads();
#pragma unroll
    for (int kk = 0; kk < 16; kk++) {
      float4 av = *(const float4*)&As[kk][ty << 2];
      float4 bv = *(const float4*)&Bs[kk][tx << 2];
      acc[0][0]+=av.x*bv.x; acc[0][1]+=av.x*bv.y; acc[0][2]+=av.x*bv.z; acc[0][3]+=av.x*bv.w;
      acc[1][0]+=av.y*bv.x; acc[1][1]+=av.y*bv.y; acc[1][2]+=av.y*bv.z; acc[1][3]+=av.y*bv.w;
      acc[2][0]+=av.z*bv.x; acc[2][1]+=av.z*bv.y; acc[2][2]+=av.z*bv.z; acc[2][3]+=av.z*bv.w;
      acc[3][0]+=av.w*bv.x; acc[3][1]+=av.w*bv.y; acc[3][2]+=av.w*bv.z; acc[3][3]+=av.w*bv.w;
    }
    __syncthreads();
  }
#pragma unroll
  for (int i = 0; i < 4; i++) {
    int m = m0 + (ty << 2) + i;
    float bi = bias[m];
    size_t off = ((size_t)b * CCH + m) * HWN + n0 + (tx << 2);
    float4 r;
    r.x = acc[i][0] + bi; r.y = acc[i][1] + bi; r.z = acc[i][2] + bi; r.w = acc[i][3] + bi;
    if (EPI == 1) {
      float4 xv = *(const float4*)(xnm + off);
      r.x *= xv.x; r.y *= xv.y; r.z *= xv.z; r.w *= xv.w;
    }
    *(float4*)(Y + off) = r;
  }
}

// ---------------- 3x3 conv as implicit GEMM (K = 384*9, zero pad) ----------
__global__ __launch_bounds__(256) void gemm3x3_kernel(
    const float* __restrict__ Wt, const float* __restrict__ bias,
    const float* __restrict__ X, float* __restrict__ Y) {
  const int K = CCH * 9;  // 3456
  int b    = blockIdx.z;
  int m0   = blockIdx.y * 64;
  int yrow = blockIdx.x;              // 64-wide N tile == one image row
  const float* Xb = X + (size_t)b * CCH * HWN;
  __shared__ float As[16][64];
  __shared__ float Bs[16][64];
  int tid = threadIdx.x, tx = tid & 15, ty = tid >> 4;
  float acc[4][4] = {{0.f}};
  int am = tid >> 2, ak = (tid & 3) << 2;
  const float* ap = Wt + (size_t)(m0 + am) * K + ak;
  for (int k0 = 0; k0 < K; k0 += 16) {
    float4 a4 = *(const float4*)ap; ap += 16;
    As[ak+0][am] = a4.x; As[ak+1][am] = a4.y; As[ak+2][am] = a4.z; As[ak+3][am] = a4.w;
#pragma unroll
    for (int e = 0; e < 4; e++) {
      int idx = tid + (e << 8);       // 0..1023
      int kl = idx >> 6, n = idx & 63;
      int kg = k0 + kl;
      int ci = kg / 9;
      int r  = kg - ci * 9;
      int dy = r / 3 - 1;
      int dx = r - (r / 3) * 3 - 1;
      int yy = yrow + dy, xx = n + dx;
      float v = 0.f;
      if ((unsigned)yy < 64u && (unsigned)xx < 64u)
        v = Xb[(size_t)ci * HWN + yy * 64 + xx];
      Bs[kl][n] = v;
    }
    __syncthreads();
#pragma unroll
    for (int kk = 0; kk < 16; kk++) {
      float4 av = *(const float4*)&As[kk][ty << 2];
      float4 bv = *(const float4*)&Bs[kk][tx << 2];
      acc[0][0]+=av.x*bv.x; acc[0][1]+=av.x*bv.y; acc[0][2]+=av.x*bv.z; acc[0][3]+=av.x*bv.w;
      acc[1][0]+=av.y*bv.x; acc[1][1]+=av.y*bv.y; acc[1][2]+=av.y*bv.z; acc[1][3]+=av.y*bv.w;
      acc[2][0]+=av.z*bv.x; acc[2][1]+=av.z*bv.y; acc[2][2]+=av.z*bv.z; acc[2][3]+=av.z*bv.w;
      acc[3][0]+=av.w*bv.x; acc[3][1]+=av.w*bv.y; acc[3][2]+=av.w*bv.z; acc[3][3]+=av.w*bv.w;
    }
    __syncthreads();
  }
#pragma unroll
  for (int i = 0; i < 4; i++) {
    int m = m0 + (ty << 2) + i;
    float bi = bias[m];
    size_t off = ((size_t)b * CCH + m) * HWN + yrow * 64 + (tx << 2);
    float4 r;
    r.x = acc[i][0] + bi; r.y = acc[i][1] + bi; r.z = acc[i][2] + bi; r.w = acc[i][3] + bi;
    *(float4*)(Y + off) = r;
  }
}

// ---------------- FFT2 passes (radix-2 DIT in LDS, natural output) ---------
__device__ __forceinline__ void fft_pass(float* zr, float* zi,
    const float* twr, const float* twi, int tid, int axis, float ds) {
#pragma unroll
  for (int stage = 0; stage < 6; stage++) {
    int half = 1 << stage;
#pragma unroll
    for (int tt = 0; tt < 8; tt++) {
      int t = tid + (tt << 8);           // 0..2047: 64 lines x 32 butterflies
      int line = t >> 5, bf = t & 31;
      int j  = bf & (half - 1);
      int i0 = ((bf >> stage) << (stage + 1)) + j;
      int i1 = i0 + half;
      int e  = j << (5 - stage);          // 64th-root exponent
      float wr = twr[e], wi = ds * twi[e];
      int a0, a1;
      if (axis == 0) { a0 = line * FFTP + i0; a1 = line * FFTP + i1; }
      else           { a0 = i0 * FFTP + line; a1 = i1 * FFTP + line; }
      float ur = zr[a0], ui = zi[a0];
      float vr = zr[a1], vi = zi[a1];
      float tr = vr * wr - vi * wi;
      float ti = vr * wi + vi * wr;
      zr[a0] = ur + tr; zi[a0] = ui + ti;
      zr[a1] = ur - tr; zi[a1] = ui - ti;
    }
    __syncthreads();
  }
}

// --------- fused: circular-conv(q,k) via FFT + topk thresh + softmax + *v ---
__global__ __launch_bounds__(256) void fft_topk_kernel(
    const float* __restrict__ q, const float* __restrict__ kkb,
    const float* __restrict__ v, float* __restrict__ F4) {
  __shared__ float zr[64 * FFTP], zi[64 * FFTP];
  __shared__ float twr[32], twi[32];
  __shared__ unsigned hist[256];
  __shared__ unsigned su2[2];
  __shared__ float sred[5];
  int tid = threadIdx.x;
  size_t base = (size_t)blockIdx.x * HWN;
  // load z = q + i*k, doubly bit-reversed for DIT-natural output
  for (int i = tid; i < HWN; i += 256) {
    int y = i >> 6, x = i & 63;
    int slot = br6(y) * FFTP + br6(x);
    zr[slot] = q[base + i];
    zi[slot] = kkb[base + i];
  }
  if (tid < 32) {
    float ang = (float)tid * 0.0981747704246810387f;  // 2*pi/64
    twr[tid] = cosf(ang);
    twi[tid] = -sinf(ang);                            // forward e^{-i theta}
  }
  __syncthreads();
  fft_pass(zr, zi, twr, twi, tid, 0, 1.f);
  fft_pass(zr, zi, twr, twi, tid, 1, 1.f);
  // split Z into Fq,Fk via Hermitian symmetry; P = Fq*Fk; store P bit-reversed
  float prr[16], pir[16];
#pragma unroll
  for (int c = 0; c < 16; c++) {
    int i = tid + (c << 8);
    int ky = i >> 6, kx = i & 63;
    float sr = zr[ky * FFTP + kx], si = zi[ky * FFTP + kx];
    int kyn = (64 - ky) & 63, kxn = (64 - kx) & 63;
    float nr = zr[kyn * FFTP + kxn], ni = zi[kyn * FFTP + kxn];
    float fqr = 0.5f * (sr + nr), fqi = 0.5f * (si - ni);
    float fkr = 0.5f * (si + ni), fki = 0.5f * (nr - sr);
    prr[c] = fqr * fkr - fqi * fki;
    pir[c] = fqr * fki + fqi * fkr;
  }
  __syncthreads();
#pragma unroll
  for (int c = 0; c < 16; c++) {
    int i = tid + (c << 8);
    int ky = i >> 6, kx = i & 63;
    int slot = br6(ky) * FFTP + br6(kx);
    zr[slot] = prr[c];
    zi[slot] = pir[c];
  }
  __syncthreads();
  fft_pass(zr, zi, twr, twi, tid, 0, -1.f);
  fft_pass(zr, zi, twr, twi, tid, 1, -1.f);
  // zr[y*P+x] = 4096 * A[y,x]
  const float scale = 1.0f / 4096.0f;
  // row max
  float lm = -3.0e38f;
  for (int i = tid; i < HWN; i += 256) {
    int y = i >> 6, x = i & 63;
    lm = fmaxf(lm, zr[y * FFTP + x]);
  }
  lm = wave_max(lm);
  if ((tid & 63) == 0) sred[tid >> 6] = lm;
  __syncthreads();
  if (tid == 0) sred[4] = fmaxf(fmaxf(sred[0], sred[1]), fmaxf(sred[2], sred[3]));
  __syncthreads();
  float am = sred[4] * scale;
  // 4-pass byte radix select: exact 512th-largest key
  unsigned prefix = 0; int kr = KSEL;
  for (int pass = 0; pass < 4; pass++) {
    int shift = 24 - (pass << 3);
    hist[tid] = 0;
    __syncthreads();
    for (int i = tid; i < HWN; i += 256) {
      int y = i >> 6, x = i & 63;
      unsigned u = f2key(zr[y * FFTP + x] * scale);
      if (((u ^ prefix) >> shift) <= 0xFFu)    // prefix bits above this byte match
        atomicAdd(&hist[(u >> shift) & 255u], 1u);
    }
    __syncthreads();
#pragma unroll
    for (int off = 1; off < 256; off <<= 1) {  // suffix sum
      unsigned t = (tid + off < 256) ? hist[tid + off] : 0u;
      __syncthreads();
      hist[tid] += t;
      __syncthreads();
    }
    unsigned sv = hist[tid];
    unsigned svn = (tid < 255) ? hist[tid + 1] : 0u;
    if (sv >= (unsigned)kr && svn < (unsigned)kr) { su2[0] = (unsigned)tid; su2[1] = svn; }
    __syncthreads();
    prefix |= su2[0] << shift;
    kr -= (int)su2[1];
    __syncthreads();
  }
  unsigned thr = prefix;
  // sum exp over selected (a >= t  <=>  key >= thr)
  float lsum = 0.f;
  for (int i = tid; i < HWN; i += 256) {
    int y = i >> 6, x = i & 63;
    float a = zr[y * FFTP + x] * scale;
    if (f2key(a) >= thr) lsum += expf(a - am);
  }
  lsum = wave_sum(lsum);
  if ((tid & 63) == 0) sred[tid >> 6] = lsum;
  __syncthreads();
  if (tid == 0) sred[4] = 1.0f / (sred[0] + sred[1] + sred[2] + sred[3]);
  __syncthreads();
  float inv = sred[4];
  for (int i = tid; i < HWN; i += 256) {
    int y = i >> 6, x = i & 63;
    float a = zr[y * FFTP + x] * scale;
    float w = (f2key(a) >= thr) ? expf(a - am) * inv : 0.f;
    F4[base + i] = v[base + i] * w;
  }
}

extern "C" void kernel_launch(void* const* d_in, const int* in_sizes, int n_in,
                              void* d_out, int out_size, void* d_ws, size_t ws_size,
                              hipStream_t stream) {
  const float* x     = (const float*)d_in[0];
  const float* gamma = (const float*)d_in[1];
  const float* beta  = (const float*)d_in[2];
  const float* wq    = (const float*)d_in[3];
  const float* bq    = (const float*)d_in[4];
  const float* wk    = (const float*)d_in[5];
  const float* bk    = (const float*)d_in[6];
  const float* wv    = (const float*)d_in[7];
  const float* bv    = (const float*)d_in[8];
  const float* wf    = (const float*)d_in[9];
  const float* bf    = (const float*)d_in[10];
  float* out = (float*)d_out;

  const size_t NEL = (size_t)BATCH * CCH * HWN;  // 12,582,912
  float* xn = (float*)d_ws;      // xn
  float* qb = xn + NEL;          // q, later F4
  float* kb = qb + NEL;          // k
  float* vb = kb + NEL;          // v        total 192 MiB of d_ws

  gn_kernel<<<dim3(BATCH * NG), dim3(256), 0, stream>>>(x, gamma, beta, xn);
  dim3 gg(64, 6, BATCH);
  gemm1x1_kernel<0><<<gg, dim3(256), 0, stream>>>(wq, bq, xn, nullptr, qb);
  gemm3x3_kernel<<<gg, dim3(256), 0, stream>>>(wk, bk, xn, kb);
  gemm1x1_kernel<0><<<gg, dim3(256), 0, stream>>>(wv, bv, xn, nullptr, vb);
  fft_topk_kernel<<<dim3(BATCH * CCH), dim3(256), 0, stream>>>(qb, kb, vb, qb);
  gemm1x1_kernel<1><<<gg, dim3(256), 0, stream>>>(wf, bf, qb, xn, out);
}

// Round 2
// 827.248 us; speedup vs baseline: 2.6335x; 2.6335x over previous
//
#include <hip/hip_runtime.h>
#include <hip/hip_fp16.h>
#include <math.h>

#define CCH  384
#define BATCH 8
#define HWN  4096
#define NG   32
#define CPG  12
#define KSEL 512
#define FFTP 65   // FFT LDS pitch
#define LP   40   // mm LDS pitch (bf16 units): bank-optimal for ds_read_b128

typedef short v8s  __attribute__((ext_vector_type(8)));   // 8 bf16 (4 VGPRs)
typedef float v16f __attribute__((ext_vector_type(16)));  // 32x32 acc

#define MFMA_B16(A_,B_,C_) __builtin_amdgcn_mfma_f32_32x32x16_bf16((A_),(B_),(C_),0,0,0)

__device__ __forceinline__ unsigned br6(unsigned i) {
  return ((i&1u)<<5)|((i&2u)<<3)|((i&4u)<<1)|((i&8u)>>1)|((i&16u)>>3)|((i&32u)>>5);
}
__device__ __forceinline__ unsigned f2key(float f) {
  unsigned u = __float_as_uint(f);
  return (u & 0x80000000u) ? ~u : (u | 0x80000000u);
}
__device__ __forceinline__ float wave_max(float v) {
#pragma unroll
  for (int o = 32; o > 0; o >>= 1) v = fmaxf(v, __shfl_down(v, o, 64));
  return v;
}
__device__ __forceinline__ float wave_sum(float v) {
#pragma unroll
  for (int o = 32; o > 0; o >>= 1) v += __shfl_down(v, o, 64);
  return v;
}
__device__ __forceinline__ unsigned short bf16_rne(float f) {
  unsigned u = __float_as_uint(f);
  return (unsigned short)((u + 0x7fffu + ((u >> 16) & 1u)) >> 16);
}
__device__ __forceinline__ float bf2f(unsigned short h) {
  return __uint_as_float(((unsigned)h) << 16);
}

// ---------------- group stats (mu, rsqrt(var+eps)) per (b,g) ----------------
__global__ __launch_bounds__(256) void stats_kernel(const float* __restrict__ x,
                                                    float2* __restrict__ gs) {
  int b = blockIdx.x >> 5, g = blockIdx.x & 31;
  size_t base = ((size_t)b * CCH + (size_t)g * CPG) * HWN;
  const float4* xp = (const float4*)(x + base);
  int tid = threadIdx.x;
  const int N4 = CPG * HWN / 4;
  float s = 0.f, ss = 0.f;
  for (int i = tid; i < N4; i += 256) {
    float4 v = xp[i];
    s  += (v.x + v.y) + (v.z + v.w);
    ss += (v.x*v.x + v.y*v.y) + (v.z*v.z + v.w*v.w);
  }
  s = wave_sum(s); ss = wave_sum(ss);
  __shared__ float sb[4], qb[4];
  if ((tid & 63) == 0) { sb[tid >> 6] = s; qb[tid >> 6] = ss; }
  __syncthreads();
  if (tid == 0) {
    float S = sb[0]+sb[1]+sb[2]+sb[3], Q = qb[0]+qb[1]+qb[2]+qb[3];
    float inv = 1.0f / (float)(CPG * HWN);
    float mu = S * inv;
    float var = Q * inv - mu * mu;
    gs[blockIdx.x] = make_float2(mu, rsqrtf(var + 1e-5f));
  }
}

// ------------- weight pack: fp32 -> bf16 hi + bf16 lo (2-term split) --------
__global__ __launch_bounds__(256) void pack_split_k(const float* __restrict__ w,
    unsigned short* __restrict__ hi, unsigned short* __restrict__ lo, int n) {
  int i = blockIdx.x * 256 + threadIdx.x;
  if (i >= n) return;
  float f = w[i];
  unsigned short h = bf16_rne(f);
  hi[i] = h;
  lo[i] = bf16_rne(f - bf2f(h));
}
// wk[m][ci][r] (r=3x3 tap) -> Wk[r][m][ci] hi/lo
__global__ __launch_bounds__(256) void pack9_k(const float* __restrict__ w,
    unsigned short* __restrict__ hi, unsigned short* __restrict__ lo) {
  int i = blockIdx.x * 256 + threadIdx.x;     // 0..147455 == m*384+ci
  int r = blockIdx.y;
  float f = w[(size_t)i * 9 + r];
  unsigned short h = bf16_rne(f);
  size_t o = (size_t)r * 147456 + i;
  hi[o] = h;
  lo[o] = bf16_rne(f - bf2f(h));
}

// ---- transpose NCHW fp32 -> NHWC bf16 hi(/lo); FUSE=1 applies GroupNorm ----
template<int FUSE, int SPLIT>
__global__ __launch_bounds__(256) void trans_kernel(const float* __restrict__ in,
    const float2* __restrict__ gs, const float* __restrict__ gamma,
    const float* __restrict__ beta,
    unsigned short* __restrict__ oh, unsigned short* __restrict__ ol) {
  __shared__ float ts[64][65];
  int tid = threadIdx.x;
  int b = blockIdx.z, c0 = blockIdx.y * 64, p0 = blockIdx.x * 64;
#pragma unroll
  for (int i = 0; i < 4; ++i) {
    int idx = tid + (i << 8);
    int row = idx >> 4, col = (idx & 15) << 2;
    float4 v = *(const float4*)&in[((size_t)b*CCH + c0 + row)*HWN + p0 + col];
    if (FUSE) {
      int c = c0 + row;
      float2 st = gs[(b << 5) + c / CPG];
      float a = gamma[c] * st.y, bb = beta[c] - st.x * a;
      v.x = v.x*a+bb; v.y = v.y*a+bb; v.z = v.z*a+bb; v.w = v.w*a+bb;
    }
    ts[row][col] = v.x; ts[row][col+1] = v.y; ts[row][col+2] = v.z; ts[row][col+3] = v.w;
  }
  __syncthreads();
#pragma unroll
  for (int i = 0; i < 2; ++i) {
    int idx = tid + (i << 8);
    int p = idx >> 3, cgp = (idx & 7) << 3;
    unsigned short h8[8] __attribute__((aligned(16)));
    unsigned short l8[8] __attribute__((aligned(16)));
#pragma unroll
    for (int j = 0; j < 8; ++j) {
      float f = ts[cgp + j][p];
      unsigned short hb = bf16_rne(f);
      h8[j] = hb;
      if (SPLIT) l8[j] = bf16_rne(f - bf2f(hb));
    }
    size_t o = ((size_t)b*HWN + p0 + p)*CCH + c0 + cgp;
    *(uint4*)&oh[o] = *(const uint4*)h8;
    if (SPLIT) *(uint4*)&ol[o] = *(const uint4*)l8;
  }
}

// ------------- MFMA GEMM, bf16 2-term split (3 MFMAs per step) --------------
// Y[b,m,n] = sum_{r,k} W[r][m][k] * X[b, pos(n,r), k] + bias[m]
// A (weights) packed [TAPS][384][384] bf16 hi/lo; B (acts) NHWC bf16 hi/lo.
// OUT: 0 = fp32 NCHW, 1 = fp16 NCHW, 2 = fp32 NCHW * (xnT_h+xnT_l) -> d_out
template<int TAPS, int OUT>
__global__ __launch_bounds__(256, 2) void mm_kernel(
    const unsigned short* __restrict__ Ahg, const unsigned short* __restrict__ Alg,
    const float* __restrict__ bias,
    const unsigned short* __restrict__ Bhg, const unsigned short* __restrict__ Blg,
    const unsigned short* __restrict__ xnTh, const unsigned short* __restrict__ xnTl,
    void* __restrict__ Yv) {
  __shared__ unsigned short Ah_s[128*LP], Al_s[128*LP], Bh_s[128*LP], Bl_s[128*LP];
  int tid = threadIdx.x;
  int b = blockIdx.z, m0 = blockIdx.y * 128, n0 = blockIdx.x * 128;
  int y0 = blockIdx.x * 2;                 // tile = image rows y0, y0+1
  int u0row = tid >> 2, cg = tid & 3;      // staging atom: 16B = 8 bf16
  int lds0 = u0row * LP + cg * 8, lds1 = lds0 + 64 * LP;
  size_t aoff0 = (size_t)(m0 + u0row) * CCH + cg * 8;
  size_t aoff1 = aoff0 + (size_t)64 * CCH;
  int lane = tid & 63, wm = tid >> 7, wn = (tid >> 6) & 1;
  int lm = lane & 31, lh = lane >> 5;
  int arow = (wm * 64 + lm) * LP, brow = (wn * 64 + lm) * LP;

  v16f acc[2][2];
#pragma unroll
  for (int t = 0; t < 2; ++t)
#pragma unroll
    for (int s = 0; s < 2; ++s)
#pragma unroll
      for (int g = 0; g < 16; ++g) acc[t][s][g] = 0.f;

  for (int r = 0; r < TAPS; ++r) {
    int dy = (TAPS == 9) ? r / 3 - 1 : 0;
    int dx = (TAPS == 9) ? r % 3 - 1 : 0;
    int px = u0row + dx;
    int py0 = y0 + dy, py1 = y0 + 1 + dy;
    bool okx = (unsigned)px < 64u;
    bool ok0 = okx && ((unsigned)py0 < 64u);
    bool ok1 = okx && ((unsigned)py1 < 64u);
    size_t boff0 = ((size_t)b * HWN + py0 * 64 + px) * CCH + cg * 8;
    size_t boff1 = ((size_t)b * HWN + py1 * 64 + px) * CCH + cg * 8;
    const unsigned short* Arh = Ahg + (size_t)r * CCH * CCH;
    const unsigned short* Arl = Alg + (size_t)r * CCH * CCH;
    for (int c0 = 0; c0 < CCH; c0 += 32) {
      uint4 zf; zf.x = zf.y = zf.z = zf.w = 0u;
      uint4 vah0 = *(const uint4*)(Arh + aoff0 + c0);
      uint4 val0 = *(const uint4*)(Arl + aoff0 + c0);
      uint4 vah1 = *(const uint4*)(Arh + aoff1 + c0);
      uint4 val1 = *(const uint4*)(Arl + aoff1 + c0);
      uint4 vbh0 = ok0 ? *(const uint4*)(Bhg + boff0 + c0) : zf;
      uint4 vbl0 = ok0 ? *(const uint4*)(Blg + boff0 + c0) : zf;
      uint4 vbh1 = ok1 ? *(const uint4*)(Bhg + boff1 + c0) : zf;
      uint4 vbl1 = ok1 ? *(const uint4*)(Blg + boff1 + c0) : zf;
      __syncthreads();
      *(uint4*)&Ah_s[lds0] = vah0; *(uint4*)&Al_s[lds0] = val0;
      *(uint4*)&Ah_s[lds1] = vah1; *(uint4*)&Al_s[lds1] = val1;
      *(uint4*)&Bh_s[lds0] = vbh0; *(uint4*)&Bl_s[lds0] = vbl0;
      *(uint4*)&Bh_s[lds1] = vbh1; *(uint4*)&Bl_s[lds1] = vbl1;
      __syncthreads();
#pragma unroll
      for (int h = 0; h < 2; ++h) {
        int co = h * 16 + lh * 8;
        v8s a0h = *(const v8s*)&Ah_s[arow + co];
        v8s a1h = *(const v8s*)&Ah_s[arow + 32*LP + co];
        v8s a0l = *(const v8s*)&Al_s[arow + co];
        v8s a1l = *(const v8s*)&Al_s[arow + 32*LP + co];
        v8s b0h = *(const v8s*)&Bh_s[brow + co];
        v8s b1h = *(const v8s*)&Bh_s[brow + 32*LP + co];
        v8s b0l = *(const v8s*)&Bl_s[brow + co];
        v8s b1l = *(const v8s*)&Bl_s[brow + 32*LP + co];
        acc[0][0] = MFMA_B16(a0h, b0h, acc[0][0]);
        acc[0][0] = MFMA_B16(a0h, b0l, acc[0][0]);
        acc[0][0] = MFMA_B16(a0l, b0h, acc[0][0]);
        acc[0][1] = MFMA_B16(a0h, b1h, acc[0][1]);
        acc[0][1] = MFMA_B16(a0h, b1l, acc[0][1]);
        acc[0][1] = MFMA_B16(a0l, b1h, acc[0][1]);
        acc[1][0] = MFMA_B16(a1h, b0h, acc[1][0]);
        acc[1][0] = MFMA_B16(a1h, b0l, acc[1][0]);
        acc[1][0] = MFMA_B16(a1l, b0h, acc[1][0]);
        acc[1][1] = MFMA_B16(a1h, b1h, acc[1][1]);
        acc[1][1] = MFMA_B16(a1h, b1l, acc[1][1]);
        acc[1][1] = MFMA_B16(a1l, b1h, acc[1][1]);
      }
    }
  }
  // epilogue: C/D layout col=lane&31, row=(g&3)+8*(g>>2)+4*(lane>>5)
#pragma unroll
  for (int t = 0; t < 2; ++t) {
    int mb = m0 + wm * 64 + t * 32;
#pragma unroll
    for (int s = 0; s < 2; ++s) {
      int n = n0 + wn * 64 + s * 32 + lm;
#pragma unroll
      for (int g = 0; g < 16; ++g) {
        int m = mb + (g & 3) + ((g >> 2) << 3) + (lh << 2);
        float val = acc[t][s][g] + bias[m];
        size_t oidx = ((size_t)b * CCH + m) * HWN + n;
        if (OUT == 0) {
          ((float*)Yv)[oidx] = val;
        } else if (OUT == 1) {
          ((__half*)Yv)[oidx] = __float2half(val);
        } else {
          size_t tix = ((size_t)b * HWN + n) * CCH + m;
          float xnv = bf2f(xnTh[tix]) + bf2f(xnTl[tix]);
          ((float*)Yv)[oidx] = val * xnv;
        }
      }
    }
  }
}

// ---------------- FFT2 passes (radix-2 DIT in LDS, natural output) ---------
__device__ __forceinline__ void fft_pass(float* zr, float* zi,
    const float* twr, const float* twi, int tid, int axis, float ds) {
#pragma unroll
  for (int stage = 0; stage < 6; stage++) {
    int half = 1 << stage;
#pragma unroll
    for (int tt = 0; tt < 8; tt++) {
      int t = tid + (tt << 8);
      int line = t >> 5, bf = t & 31;
      int j  = bf & (half - 1);
      int i0 = ((bf >> stage) << (stage + 1)) + j;
      int i1 = i0 + half;
      int e  = j << (5 - stage);
      float wr = twr[e], wi = ds * twi[e];
      int a0, a1;
      if (axis == 0) { a0 = line * FFTP + i0; a1 = line * FFTP + i1; }
      else           { a0 = i0 * FFTP + line; a1 = i1 * FFTP + line; }
      float ur = zr[a0], ui = zi[a0];
      float vr = zr[a1], vi = zi[a1];
      float tr = vr * wr - vi * wi;
      float ti = vr * wi + vi * wr;
      zr[a0] = ur + tr; zi[a0] = ui + ti;
      zr[a1] = ur - tr; zi[a1] = ui - ti;
    }
    __syncthreads();
  }
}

// --------- fused: circ-conv(q,k) via FFT + exact top-k + softmax + *v -------
// F4 may alias q (block reads its q range fully before writing F4).
__global__ __launch_bounds__(256) void fft_topk_kernel(
    const float* q, const float* __restrict__ kkb,
    const __half* __restrict__ v, float* F4) {
  __shared__ float zr[64 * FFTP], zi[64 * FFTP];
  __shared__ float twr[32], twi[32];
  __shared__ unsigned hist[256];
  __shared__ unsigned su2[2];
  __shared__ float sred[5];
  int tid = threadIdx.x;
  size_t base = (size_t)blockIdx.x * HWN;
  for (int i = tid; i < HWN; i += 256) {
    int y = i >> 6, x = i & 63;
    int slot = br6(y) * FFTP + br6(x);
    zr[slot] = q[base + i];
    zi[slot] = kkb[base + i];
  }
  if (tid < 32) {
    float ang = (float)tid * 0.0981747704246810387f;
    twr[tid] = cosf(ang);
    twi[tid] = -sinf(ang);
  }
  __syncthreads();
  fft_pass(zr, zi, twr, twi, tid, 0, 1.f);
  fft_pass(zr, zi, twr, twi, tid, 1, 1.f);
  float prr[16], pir[16];
#pragma unroll
  for (int c = 0; c < 16; c++) {
    int i = tid + (c << 8);
    int ky = i >> 6, kx = i & 63;
    float sr = zr[ky * FFTP + kx], si = zi[ky * FFTP + kx];
    int kyn = (64 - ky) & 63, kxn = (64 - kx) & 63;
    float nr = zr[kyn * FFTP + kxn], ni = zi[kyn * FFTP + kxn];
    float fqr = 0.5f * (sr + nr), fqi = 0.5f * (si - ni);
    float fkr = 0.5f * (si + ni), fki = 0.5f * (nr - sr);
    prr[c] = fqr * fkr - fqi * fki;
    pir[c] = fqr * fki + fqi * fkr;
  }
  __syncthreads();
#pragma unroll
  for (int c = 0; c < 16; c++) {
    int i = tid + (c << 8);
    int ky = i >> 6, kx = i & 63;
    int slot = br6(ky) * FFTP + br6(kx);
    zr[slot] = prr[c];
    zi[slot] = pir[c];
  }
  __syncthreads();
  fft_pass(zr, zi, twr, twi, tid, 0, -1.f);
  fft_pass(zr, zi, twr, twi, tid, 1, -1.f);
  const float scale = 1.0f / 4096.0f;
  float lm = -3.0e38f;
  for (int i = tid; i < HWN; i += 256) {
    int y = i >> 6, x = i & 63;
    lm = fmaxf(lm, zr[y * FFTP + x]);
  }
  lm = wave_max(lm);
  if ((tid & 63) == 0) sred[tid >> 6] = lm;
  __syncthreads();
  if (tid == 0) sred[4] = fmaxf(fmaxf(sred[0], sred[1]), fmaxf(sred[2], sred[3]));
  __syncthreads();
  float am = sred[4] * scale;
  unsigned prefix = 0; int kr = KSEL;
  for (int pass = 0; pass < 4; pass++) {
    int shift = 24 - (pass << 3);
    hist[tid] = 0;
    __syncthreads();
    for (int i = tid; i < HWN; i += 256) {
      int y = i >> 6, x = i & 63;
      unsigned u = f2key(zr[y * FFTP + x] * scale);
      if (((u ^ prefix) >> shift) <= 0xFFu)
        atomicAdd(&hist[(u >> shift) & 255u], 1u);
    }
    __syncthreads();
#pragma unroll
    for (int off = 1; off < 256; off <<= 1) {
      unsigned t = (tid + off < 256) ? hist[tid + off] : 0u;
      __syncthreads();
      hist[tid] += t;
      __syncthreads();
    }
    unsigned sv = hist[tid];
    unsigned svn = (tid < 255) ? hist[tid + 1] : 0u;
    if (sv >= (unsigned)kr && svn < (unsigned)kr) { su2[0] = (unsigned)tid; su2[1] = svn; }
    __syncthreads();
    prefix |= su2[0] << shift;
    kr -= (int)su2[1];
    __syncthreads();
  }
  unsigned thr = prefix;
  float lsum = 0.f;
  for (int i = tid; i < HWN; i += 256) {
    int y = i >> 6, x = i & 63;
    float a = zr[y * FFTP + x] * scale;
    if (f2key(a) >= thr) lsum += expf(a - am);
  }
  lsum = wave_sum(lsum);
  if ((tid & 63) == 0) sred[tid >> 6] = lsum;
  __syncthreads();
  if (tid == 0) sred[4] = 1.0f / (sred[0] + sred[1] + sred[2] + sred[3]);
  __syncthreads();
  float inv = sred[4];
  for (int i = tid; i < HWN; i += 256) {
    int y = i >> 6, x = i & 63;
    float a = zr[y * FFTP + x] * scale;
    float w = (f2key(a) >= thr) ? expf(a - am) * inv : 0.f;
    F4[base + i] = __half2float(v[base + i]) * w;
  }
}

extern "C" void kernel_launch(void* const* d_in, const int* in_sizes, int n_in,
                              void* d_out, int out_size, void* d_ws, size_t ws_size,
                              hipStream_t stream) {
  const float* x     = (const float*)d_in[0];
  const float* gamma = (const float*)d_in[1];
  const float* beta  = (const float*)d_in[2];
  const float* wq    = (const float*)d_in[3];
  const float* bq    = (const float*)d_in[4];
  const float* wk    = (const float*)d_in[5];
  const float* bk    = (const float*)d_in[6];
  const float* wv    = (const float*)d_in[7];
  const float* bv    = (const float*)d_in[8];
  const float* wf    = (const float*)d_in[9];
  const float* bf    = (const float*)d_in[10];

  const size_t NEL = (size_t)BATCH * CCH * HWN;   // 12,582,912
  const size_t WSZ = (size_t)CCH * CCH;           // 147,456

  unsigned short* xnTh = (unsigned short*)d_ws;        // bf16 NHWC hi
  unsigned short* xnTl = xnTh + NEL;                   // bf16 NHWC lo
  float*  qC  = (float*)(xnTl + NEL);                  // q fp32 -> F4 fp32
  float*  kD  = qC + NEL;                              // k fp32 -> F4T hi/lo
  __half* vE  = (__half*)(kD + NEL);                   // v fp16
  unsigned short* W = (unsigned short*)(vE + NEL);
  unsigned short* Wqh = W;
  unsigned short* Wql = Wqh + WSZ;
  unsigned short* Wvh = Wql + WSZ;
  unsigned short* Wvl = Wvh + WSZ;
  unsigned short* Wfh = Wvl + WSZ;
  unsigned short* Wfl = Wfh + WSZ;
  unsigned short* Wkh = Wfl + WSZ;                     // 9*147456
  unsigned short* Wkl = Wkh + 9 * WSZ;
  float2* gs = (float2*)(Wkl + 9 * WSZ);
  unsigned short* F4Th = (unsigned short*)kD;          // reuse k region
  unsigned short* F4Tl = F4Th + NEL;

  pack_split_k<<<dim3(576), dim3(256), 0, stream>>>(wq, Wqh, Wql, (int)WSZ);
  pack_split_k<<<dim3(576), dim3(256), 0, stream>>>(wv, Wvh, Wvl, (int)WSZ);
  pack_split_k<<<dim3(576), dim3(256), 0, stream>>>(wf, Wfh, Wfl, (int)WSZ);
  pack9_k<<<dim3(576, 9), dim3(256), 0, stream>>>(wk, Wkh, Wkl);
  stats_kernel<<<dim3(BATCH * NG), dim3(256), 0, stream>>>(x, gs);
  trans_kernel<1, 1><<<dim3(64, 6, BATCH), dim3(256), 0, stream>>>(
      x, gs, gamma, beta, xnTh, xnTl);

  dim3 gm(32, 3, BATCH);
  mm_kernel<1, 0><<<gm, dim3(256), 0, stream>>>(Wqh, Wql, bq, xnTh, xnTl,
                                                nullptr, nullptr, qC);
  mm_kernel<9, 0><<<gm, dim3(256), 0, stream>>>(Wkh, Wkl, bk, xnTh, xnTl,
                                                nullptr, nullptr, kD);
  mm_kernel<1, 1><<<gm, dim3(256), 0, stream>>>(Wvh, Wvl, bv, xnTh, xnTl,
                                                nullptr, nullptr, vE);

  fft_topk_kernel<<<dim3(BATCH * CCH), dim3(256), 0, stream>>>(qC, kD, vE, qC);

  trans_kernel<0, 1><<<dim3(64, 6, BATCH), dim3(256), 0, stream>>>(
      qC, nullptr, nullptr, nullptr, F4Th, F4Tl);

  mm_kernel<1, 2><<<gm, dim3(256), 0, stream>>>(Wfh, Wfl, bf, F4Th, F4Tl,
                                                xnTh, xnTl, d_out);
}

// Round 3
// 694.326 us; speedup vs baseline: 3.1376x; 1.1914x over previous
//
#include <hip/hip_runtime.h>
#include <hip/hip_fp16.h>
#include <math.h>

#define CCH  384
#define BATCH 8
#define HWN  4096
#define NG   32
#define CPG  12
#define KSEL 512
#define FFTP 65   // FFT LDS pitch
#define LP   40   // mm LDS pitch (bf16 units)

typedef short v8s  __attribute__((ext_vector_type(8)));   // 8 bf16 (4 VGPRs)
typedef float v16f __attribute__((ext_vector_type(16)));  // 32x32 acc

#define MFMA_B16(A_,B_,C_) __builtin_amdgcn_mfma_f32_32x32x16_bf16((A_),(B_),(C_),0,0,0)

__device__ __forceinline__ unsigned br6(unsigned i) {
  return ((i&1u)<<5)|((i&2u)<<3)|((i&4u)<<1)|((i&8u)>>1)|((i&16u)>>3)|((i&32u)>>5);
}
__device__ __forceinline__ unsigned f2key(float f) {
  unsigned u = __float_as_uint(f);
  return (u & 0x80000000u) ? ~u : (u | 0x80000000u);
}
__device__ __forceinline__ float wave_max(float v) {
#pragma unroll
  for (int o = 32; o > 0; o >>= 1) v = fmaxf(v, __shfl_down(v, o, 64));
  return v;
}
__device__ __forceinline__ float wave_sum(float v) {
#pragma unroll
  for (int o = 32; o > 0; o >>= 1) v += __shfl_down(v, o, 64);
  return v;
}
__device__ __forceinline__ unsigned short bf16_rne(float f) {
  unsigned u = __float_as_uint(f);
  return (unsigned short)((u + 0x7fffu + ((u >> 16) & 1u)) >> 16);
}
__device__ __forceinline__ float bf2f(unsigned short h) {
  return __uint_as_float(((unsigned)h) << 16);
}

// ---------------- group stats (mu, rsqrt(var+eps)) per (b,g) ----------------
__global__ __launch_bounds__(256) void stats_kernel(const float* __restrict__ x,
                                                    float2* __restrict__ gs) {
  int b = blockIdx.x >> 5, g = blockIdx.x & 31;
  size_t base = ((size_t)b * CCH + (size_t)g * CPG) * HWN;
  const float4* xp = (const float4*)(x + base);
  int tid = threadIdx.x;
  const int N4 = CPG * HWN / 4;
  float s = 0.f, ss = 0.f;
  for (int i = tid; i < N4; i += 256) {
    float4 v = xp[i];
    s  += (v.x + v.y) + (v.z + v.w);
    ss += (v.x*v.x + v.y*v.y) + (v.z*v.z + v.w*v.w);
  }
  s = wave_sum(s); ss = wave_sum(ss);
  __shared__ float sb[4], qb[4];
  if ((tid & 63) == 0) { sb[tid >> 6] = s; qb[tid >> 6] = ss; }
  __syncthreads();
  if (tid == 0) {
    float S = sb[0]+sb[1]+sb[2]+sb[3], Q = qb[0]+qb[1]+qb[2]+qb[3];
    float inv = 1.0f / (float)(CPG * HWN);
    float mu = S * inv;
    float var = Q * inv - mu * mu;
    gs[blockIdx.x] = make_float2(mu, rsqrtf(var + 1e-5f));
  }
}

// ------------- weight pack: fp32 -> bf16 hi + bf16 lo (2-term split) --------
__global__ __launch_bounds__(256) void pack_split_k(const float* __restrict__ w,
    unsigned short* __restrict__ hi, unsigned short* __restrict__ lo, int n) {
  int i = blockIdx.x * 256 + threadIdx.x;
  if (i >= n) return;
  float f = w[i];
  unsigned short h = bf16_rne(f);
  hi[i] = h;
  lo[i] = bf16_rne(f - bf2f(h));
}
// wk[m][ci][r] (r=3x3 tap) -> Wk[r][m][ci] hi/lo
__global__ __launch_bounds__(256) void pack9_k(const float* __restrict__ w,
    unsigned short* __restrict__ hi, unsigned short* __restrict__ lo) {
  int i = blockIdx.x * 256 + threadIdx.x;     // 0..147455 == m*384+ci
  int r = blockIdx.y;
  float f = w[(size_t)i * 9 + r];
  unsigned short h = bf16_rne(f);
  size_t o = (size_t)r * 147456 + i;
  hi[o] = h;
  lo[o] = bf16_rne(f - bf2f(h));
}

// ---- transpose NCHW fp32 -> NHWC bf16 hi(/lo); FUSE=1 applies GroupNorm ----
template<int FUSE, int SPLIT>
__global__ __launch_bounds__(256) void trans_kernel(const float* __restrict__ in,
    const float2* __restrict__ gs, const float* __restrict__ gamma,
    const float* __restrict__ beta,
    unsigned short* __restrict__ oh, unsigned short* __restrict__ ol) {
  __shared__ float ts[64][65];
  int tid = threadIdx.x;
  int b = blockIdx.z, c0 = blockIdx.y * 64, p0 = blockIdx.x * 64;
#pragma unroll
  for (int i = 0; i < 4; ++i) {
    int idx = tid + (i << 8);
    int row = idx >> 4, col = (idx & 15) << 2;
    float4 v = *(const float4*)&in[((size_t)b*CCH + c0 + row)*HWN + p0 + col];
    if (FUSE) {
      int c = c0 + row;
      float2 st = gs[(b << 5) + c / CPG];
      float a = gamma[c] * st.y, bb = beta[c] - st.x * a;
      v.x = v.x*a+bb; v.y = v.y*a+bb; v.z = v.z*a+bb; v.w = v.w*a+bb;
    }
    ts[row][col] = v.x; ts[row][col+1] = v.y; ts[row][col+2] = v.z; ts[row][col+3] = v.w;
  }
  __syncthreads();
#pragma unroll
  for (int i = 0; i < 2; ++i) {
    int idx = tid + (i << 8);
    int p = idx >> 3, cgp = (idx & 7) << 3;
    unsigned short h8[8] __attribute__((aligned(16)));
    unsigned short l8[8] __attribute__((aligned(16)));
#pragma unroll
    for (int j = 0; j < 8; ++j) {
      float f = ts[cgp + j][p];
      unsigned short hb = bf16_rne(f);
      h8[j] = hb;
      if (SPLIT) l8[j] = bf16_rne(f - bf2f(hb));
    }
    size_t o = ((size_t)b*HWN + p0 + p)*CCH + c0 + cgp;
    *(uint4*)&oh[o] = *(const uint4*)h8;
    if (SPLIT) *(uint4*)&ol[o] = *(const uint4*)l8;
  }
}

// ------------- MFMA GEMM, bf16 2-term split (3 MFMAs per step) --------------
// Register-prefetch pipelined K-loop: global loads for step s+1 issue right
// after the LDS stores of step s, so the MFMA block hides their latency and
// the barrier never drains vmcnt(0).
// OUT: 0 = fp32 NCHW, 1 = fp16 NCHW, 2 = fp32 NCHW * (xnT_h+xnT_l) -> d_out
template<int TAPS, int OUT>
__global__ __launch_bounds__(256, 3) void mm_kernel(
    const unsigned short* __restrict__ Ahg, const unsigned short* __restrict__ Alg,
    const float* __restrict__ bias,
    const unsigned short* __restrict__ Bhg, const unsigned short* __restrict__ Blg,
    const unsigned short* __restrict__ xnTh, const unsigned short* __restrict__ xnTl,
    void* __restrict__ Yv) {
  __shared__ unsigned short Ah_s[128*LP], Al_s[128*LP], Bh_s[128*LP], Bl_s[128*LP];
  int tid = threadIdx.x;
  int b = blockIdx.z, m0 = blockIdx.y * 128, n0 = blockIdx.x * 128;
  int y0 = blockIdx.x * 2;                 // tile = image rows y0, y0+1
  int u0row = tid >> 2, cg = tid & 3;      // staging atom: 16B = 8 bf16
  int lds0 = u0row * LP + cg * 8, lds1 = lds0 + 64 * LP;
  size_t aoff0 = (size_t)(m0 + u0row) * CCH + cg * 8;
  int lane = tid & 63, wm = tid >> 7, wn = (tid >> 6) & 1;
  int lm = lane & 31, lh = lane >> 5;
  int arow = (wm * 64 + lm) * LP, brow = (wn * 64 + lm) * LP;

  v16f acc[2][2];
#pragma unroll
  for (int t = 0; t < 2; ++t)
#pragma unroll
    for (int s = 0; s < 2; ++s)
#pragma unroll
      for (int g = 0; g < 16; ++g) acc[t][s][g] = 0.f;

  const int NS = TAPS * 12;
  uint4 ra0h, ra0l, ra1h, ra1l, rb0h, rb0l, rb1h, rb1l;

  auto issue = [&](int s) {
    int r  = (TAPS == 9) ? (s / 12) : 0;
    int c0 = (s - r * 12) * 32;
    const unsigned short* Arh = Ahg + (size_t)r * CCH * CCH + aoff0 + c0;
    const unsigned short* Arl = Alg + (size_t)r * CCH * CCH + aoff0 + c0;
    ra0h = *(const uint4*)Arh;
    ra0l = *(const uint4*)Arl;
    ra1h = *(const uint4*)(Arh + 64 * CCH);
    ra1l = *(const uint4*)(Arl + 64 * CCH);
    int dy = (TAPS == 9) ? r / 3 - 1 : 0;
    int dx = (TAPS == 9) ? r % 3 - 1 : 0;
    int px = u0row + dx;
    int py0 = y0 + dy, py1 = py0 + 1;
    bool okx = (unsigned)px < 64u;
    bool ok0 = okx && ((unsigned)py0 < 64u);
    bool ok1 = okx && ((unsigned)py1 < 64u);
    size_t boff0 = ((size_t)b * HWN + py0 * 64 + px) * CCH + cg * 8 + c0;
    size_t boff1 = ((size_t)b * HWN + py1 * 64 + px) * CCH + cg * 8 + c0;
    uint4 zf; zf.x = zf.y = zf.z = zf.w = 0u;
    rb0h = ok0 ? *(const uint4*)(Bhg + boff0) : zf;
    rb0l = ok0 ? *(const uint4*)(Blg + boff0) : zf;
    rb1h = ok1 ? *(const uint4*)(Bhg + boff1) : zf;
    rb1l = ok1 ? *(const uint4*)(Blg + boff1) : zf;
  };

  issue(0);
  for (int s = 0; s < NS; ++s) {
    __syncthreads();
    *(uint4*)&Ah_s[lds0] = ra0h; *(uint4*)&Al_s[lds0] = ra0l;
    *(uint4*)&Ah_s[lds1] = ra1h; *(uint4*)&Al_s[lds1] = ra1l;
    *(uint4*)&Bh_s[lds0] = rb0h; *(uint4*)&Bl_s[lds0] = rb0l;
    *(uint4*)&Bh_s[lds1] = rb1h; *(uint4*)&Bl_s[lds1] = rb1l;
    __syncthreads();
    if (s + 1 < NS) issue(s + 1);   // prefetch: in flight during MFMAs below
#pragma unroll
    for (int h = 0; h < 2; ++h) {
      int co = h * 16 + lh * 8;
      v8s a0h = *(const v8s*)&Ah_s[arow + co];
      v8s a1h = *(const v8s*)&Ah_s[arow + 32*LP + co];
      v8s a0l = *(const v8s*)&Al_s[arow + co];
      v8s a1l = *(const v8s*)&Al_s[arow + 32*LP + co];
      v8s b0h = *(const v8s*)&Bh_s[brow + co];
      v8s b1h = *(const v8s*)&Bh_s[brow + 32*LP + co];
      v8s b0l = *(const v8s*)&Bl_s[brow + co];
      v8s b1l = *(const v8s*)&Bl_s[brow + 32*LP + co];
      acc[0][0] = MFMA_B16(a0h, b0h, acc[0][0]);
      acc[0][0] = MFMA_B16(a0h, b0l, acc[0][0]);
      acc[0][0] = MFMA_B16(a0l, b0h, acc[0][0]);
      acc[0][1] = MFMA_B16(a0h, b1h, acc[0][1]);
      acc[0][1] = MFMA_B16(a0h, b1l, acc[0][1]);
      acc[0][1] = MFMA_B16(a0l, b1h, acc[0][1]);
      acc[1][0] = MFMA_B16(a1h, b0h, acc[1][0]);
      acc[1][0] = MFMA_B16(a1h, b0l, acc[1][0]);
      acc[1][0] = MFMA_B16(a1l, b0h, acc[1][0]);
      acc[1][1] = MFMA_B16(a1h, b1h, acc[1][1]);
      acc[1][1] = MFMA_B16(a1h, b1l, acc[1][1]);
      acc[1][1] = MFMA_B16(a1l, b1h, acc[1][1]);
    }
  }
  // epilogue: C/D layout col=lane&31, row=(g&3)+8*(g>>2)+4*(lane>>5)
#pragma unroll
  for (int t = 0; t < 2; ++t) {
    int mb = m0 + wm * 64 + t * 32;
#pragma unroll
    for (int s = 0; s < 2; ++s) {
      int n = n0 + wn * 64 + s * 32 + lm;
#pragma unroll
      for (int g = 0; g < 16; ++g) {
        int m = mb + (g & 3) + ((g >> 2) << 3) + (lh << 2);
        float val = acc[t][s][g] + bias[m];
        size_t oidx = ((size_t)b * CCH + m) * HWN + n;
        if (OUT == 0) {
          ((float*)Yv)[oidx] = val;
        } else if (OUT == 1) {
          ((__half*)Yv)[oidx] = __float2half(val);
        } else {
          size_t tix = ((size_t)b * HWN + n) * CCH + m;
          float xnv = bf2f(xnTh[tix]) + bf2f(xnTl[tix]);
          ((float*)Yv)[oidx] = val * xnv;
        }
      }
    }
  }
}

// -------- FFT2 pass: 3 fused radix-4 stages (bit-reversed in, natural out) --
__device__ __forceinline__ void fft4_pass(float* zr, float* zi,
    const float* twr, const float* twi, int tid, int axis, float ds) {
#pragma unroll
  for (int s = 0; s < 3; ++s) {
    const int h = 1 << (2 * s);            // 1, 4, 16
#pragma unroll
    for (int tt = 0; tt < 4; ++tt) {
      int t = tid + (tt << 8);             // 0..1023: 64 lines x 16 radix-4 bf
      int line = t >> 4, bf = t & 15;
      int j  = bf & (h - 1);
      int i0 = ((bf >> (2 * s)) << (2 * s + 2)) + j;
      int e1 = j << (5 - 2 * s);
      int e2 = j << (4 - 2 * s);
      float w1r = twr[e1], w1i = ds * twi[e1];
      float w2r = twr[e2], w2i = ds * twi[e2];
      int A0, st;
      if (axis == 0) { A0 = line * FFTP + i0; st = h; }
      else           { A0 = i0 * FFTP + line; st = h * FFTP; }
      int A1 = A0 + st, A2 = A1 + st, A3 = A2 + st;
      float x0r = zr[A0], x0i = zi[A0];
      float x1r = zr[A1], x1i = zi[A1];
      float x2r = zr[A2], x2i = zi[A2];
      float x3r = zr[A3], x3i = zi[A3];
      float t1r = x1r*w1r - x1i*w1i, t1i = x1r*w1i + x1i*w1r;
      float t3r = x3r*w1r - x3i*w1i, t3i = x3r*w1i + x3i*w1r;
      float u0r = x0r + t1r, u0i = x0i + t1i;
      float u1r = x0r - t1r, u1i = x0i - t1i;
      float u2r = x2r + t3r, u2i = x2i + t3i;
      float u3r = x2r - t3r, u3i = x2i - t3i;
      float c2r = u2r*w2r - u2i*w2i, c2i = u2r*w2i + u2i*w2r;
      float c3r = u3r*w2r - u3i*w2i, c3i = u3r*w2i + u3i*w2r;
      zr[A0] = u0r + c2r;      zi[A0] = u0i + c2i;
      zr[A2] = u0r - c2r;      zi[A2] = u0i - c2i;
      zr[A1] = u1r + ds*c3i;   zi[A1] = u1i - ds*c3r;
      zr[A3] = u1r - ds*c3i;   zi[A3] = u1i + ds*c3r;
    }
    __syncthreads();
  }
}

// --------- fused: circ-conv(q,k) via FFT + exact top-k + softmax + *v -------
// F4 may alias q (block reads its q range fully before writing F4).
__global__ __launch_bounds__(256) void fft_topk_kernel(
    const float* q, const float* __restrict__ kkb,
    const __half* __restrict__ v, float* F4) {
  __shared__ float zr[64 * FFTP], zi[64 * FFTP];
  __shared__ float twr[32], twi[32];
  __shared__ unsigned hist[256];
  __shared__ unsigned su2[2];
  __shared__ unsigned wtot[4];
  __shared__ float sred[5];
  int tid = threadIdx.x;
  int lane = tid & 63, w = tid >> 6;
  size_t base = (size_t)blockIdx.x * HWN;
  for (int i = tid; i < HWN; i += 256) {
    int y = i >> 6, x = i & 63;
    int slot = br6(y) * FFTP + br6(x);
    zr[slot] = q[base + i];
    zi[slot] = kkb[base + i];
  }
  if (tid < 32) {
    float ang = (float)tid * 0.0981747704246810387f;  // 2*pi/64
    twr[tid] = cosf(ang);
    twi[tid] = -sinf(ang);                            // forward e^{-i theta}
  }
  __syncthreads();
  fft4_pass(zr, zi, twr, twi, tid, 0, 1.f);
  fft4_pass(zr, zi, twr, twi, tid, 1, 1.f);
  // split Z into Fq,Fk via Hermitian symmetry; P = Fq*Fk
  float prr[16], pir[16];
#pragma unroll
  for (int c = 0; c < 16; c++) {
    int i = tid + (c << 8);
    int ky = i >> 6, kx = i & 63;
    float sr = zr[ky * FFTP + kx], si = zi[ky * FFTP + kx];
    int kyn = (64 - ky) & 63, kxn = (64 - kx) & 63;
    float nr = zr[kyn * FFTP + kxn], ni = zi[kyn * FFTP + kxn];
    float fqr = 0.5f * (sr + nr), fqi = 0.5f * (si - ni);
    float fkr = 0.5f * (si + ni), fki = 0.5f * (nr - sr);
    prr[c] = fqr * fkr - fqi * fki;
    pir[c] = fqr * fki + fqi * fkr;
  }
  __syncthreads();
#pragma unroll
  for (int c = 0; c < 16; c++) {
    int i = tid + (c << 8);
    int ky = i >> 6, kx = i & 63;
    int slot = br6(ky) * FFTP + br6(kx);
    zr[slot] = prr[c];
    zi[slot] = pir[c];
  }
  __syncthreads();
  fft4_pass(zr, zi, twr, twi, tid, 0, -1.f);
  fft4_pass(zr, zi, twr, twi, tid, 1, -1.f);
  // pull this thread's 16 A values into registers; LDS not re-read after this
  const float scale = 1.0f / 4096.0f;
  float a[16];
  unsigned key[16];
  float mx = -3.0e38f;
#pragma unroll
  for (int c = 0; c < 16; c++) {
    int i = tid + (c << 8);
    a[c] = zr[(i >> 6) * FFTP + (i & 63)] * scale;
    key[c] = f2key(a[c]);
    mx = fmaxf(mx, a[c]);
  }
  mx = wave_max(mx);
  if (lane == 0) sred[w] = mx;
  __syncthreads();
  if (tid == 0) sred[4] = fmaxf(fmaxf(sred[0], sred[1]), fmaxf(sred[2], sred[3]));
  __syncthreads();
  float am = sred[4];
  // 4-pass byte radix select (exact 512th-largest key), shuffle-based scan
  unsigned prefix = 0; int kr = KSEL;
  for (int pass = 0; pass < 4; pass++) {
    int shift = 24 - (pass << 3);
    hist[tid] = 0;
    __syncthreads();
#pragma unroll
    for (int c = 0; c < 16; c++) {
      unsigned u = key[c];
      if (((u ^ prefix) >> shift) <= 0xFFu)
        atomicAdd(&hist[(u >> shift) & 255u], 1u);
    }
    __syncthreads();
    unsigned xv = hist[tid];
#pragma unroll
    for (int o = 1; o < 64; o <<= 1) {      // intra-wave suffix scan
      unsigned t2 = __shfl_down(xv, o, 64);
      if (lane + o < 64) xv += t2;
    }
    if (lane == 0) wtot[w] = xv;
    __syncthreads();
    for (int ww = w + 1; ww < 4; ++ww) xv += wtot[ww];
    hist[tid] = xv;                          // S[t] = #keys with byte >= t
    __syncthreads();
    unsigned sv = xv;
    unsigned svn = (tid < 255) ? hist[tid + 1] : 0u;
    if (sv >= (unsigned)kr && svn < (unsigned)kr) { su2[0] = (unsigned)tid; su2[1] = svn; }
    __syncthreads();
    prefix |= su2[0] << shift;
    kr -= (int)su2[1];
  }
  unsigned thr = prefix;
  float lsum = 0.f;
#pragma unroll
  for (int c = 0; c < 16; c++)
    if (key[c] >= thr) lsum += expf(a[c] - am);
  lsum = wave_sum(lsum);
  if (lane == 0) sred[w] = lsum;
  __syncthreads();
  if (tid == 0) sred[4] = 1.0f / (sred[0] + sred[1] + sred[2] + sred[3]);
  __syncthreads();
  float inv = sred[4];
#pragma unroll
  for (int c = 0; c < 16; c++) {
    int i = tid + (c << 8);
    float wgt = (key[c] >= thr) ? expf(a[c] - am) * inv : 0.f;
    F4[base + i] = __half2float(v[base + i]) * wgt;
  }
}

extern "C" void kernel_launch(void* const* d_in, const int* in_sizes, int n_in,
                              void* d_out, int out_size, void* d_ws, size_t ws_size,
                              hipStream_t stream) {
  const float* x     = (const float*)d_in[0];
  const float* gamma = (const float*)d_in[1];
  const float* beta  = (const float*)d_in[2];
  const float* wq    = (const float*)d_in[3];
  const float* bq    = (const float*)d_in[4];
  const float* wk    = (const float*)d_in[5];
  const float* bk    = (const float*)d_in[6];
  const float* wv    = (const float*)d_in[7];
  const float* bv    = (const float*)d_in[8];
  const float* wf    = (const float*)d_in[9];
  const float* bf    = (const float*)d_in[10];

  const size_t NEL = (size_t)BATCH * CCH * HWN;   // 12,582,912
  const size_t WSZ = (size_t)CCH * CCH;           // 147,456

  unsigned short* xnTh = (unsigned short*)d_ws;        // bf16 NHWC hi
  unsigned short* xnTl = xnTh + NEL;                   // bf16 NHWC lo
  float*  qC  = (float*)(xnTl + NEL);                  // q fp32 -> F4 fp32
  float*  kD  = qC + NEL;                              // k fp32 -> F4T hi/lo
  __half* vE  = (__half*)(kD + NEL);                   // v fp16
  unsigned short* W = (unsigned short*)(vE + NEL);
  unsigned short* Wqh = W;
  unsigned short* Wql = Wqh + WSZ;
  unsigned short* Wvh = Wql + WSZ;
  unsigned short* Wvl = Wvh + WSZ;
  unsigned short* Wfh = Wvl + WSZ;
  unsigned short* Wfl = Wfh + WSZ;
  unsigned short* Wkh = Wfl + WSZ;                     // 9*147456
  unsigned short* Wkl = Wkh + 9 * WSZ;
  float2* gs = (float2*)(Wkl + 9 * WSZ);
  unsigned short* F4Th = (unsigned short*)kD;          // reuse k region
  unsigned short* F4Tl = F4Th + NEL;

  pack_split_k<<<dim3(576), dim3(256), 0, stream>>>(wq, Wqh, Wql, (int)WSZ);
  pack_split_k<<<dim3(576), dim3(256), 0, stream>>>(wv, Wvh, Wvl, (int)WSZ);
  pack_split_k<<<dim3(576), dim3(256), 0, stream>>>(wf, Wfh, Wfl, (int)WSZ);
  pack9_k<<<dim3(576, 9), dim3(256), 0, stream>>>(wk, Wkh, Wkl);
  stats_kernel<<<dim3(BATCH * NG), dim3(256), 0, stream>>>(x, gs);
  trans_kernel<1, 1><<<dim3(64, 6, BATCH), dim3(256), 0, stream>>>(
      x, gs, gamma, beta, xnTh, xnTl);

  dim3 gm(32, 3, BATCH);
  mm_kernel<1, 0><<<gm, dim3(256), 0, stream>>>(Wqh, Wql, bq, xnTh, xnTl,
                                                nullptr, nullptr, qC);
  mm_kernel<9, 0><<<gm, dim3(256), 0, stream>>>(Wkh, Wkl, bk, xnTh, xnTl,
                                                nullptr, nullptr, kD);
  mm_kernel<1, 1><<<gm, dim3(256), 0, stream>>>(Wvh, Wvl, bv, xnTh, xnTl,
                                                nullptr, nullptr, vE);

  fft_topk_kernel<<<dim3(BATCH * CCH), dim3(256), 0, stream>>>(qC, kD, vE, qC);

  trans_kernel<0, 1><<<dim3(64, 6, BATCH), dim3(256), 0, stream>>>(
      qC, nullptr, nullptr, nullptr, F4Th, F4Tl);

  mm_kernel<1, 2><<<gm, dim3(256), 0, stream>>>(Wfh, Wfl, bf, F4Th, F4Tl,
                                                xnTh, xnTl, d_out);
}